// Round 10
// baseline (377.145 us; speedup 1.0000x reference)
//
#include <hip/hip_runtime.h>

#define BB 64
#define MM 512
#define NN 512
#define NUM_SINK 20
#define SLICES 8   // workgroups per batch

// base-2 domain: exp(x) == exp2(x*log2e); K2 = log2(e)/lambda
constexpr float NEG_K2 = -(1.4426950408889634f / 0.002f);   // ~ -721.3475

__device__ __forceinline__ float exp2fast(float x) { return __builtin_amdgcn_exp2f(x); }
__device__ __forceinline__ float log2fast(float x) { return __builtin_amdgcn_logf(x); }
__device__ __forceinline__ float rcpfast(float x)  { return __builtin_amdgcn_rcpf(x); }

// coherent per-access helpers: sc-flagged global ops, no cache-wide maintenance
__device__ __forceinline__ float ld_coh(const float* p) {
    return __hip_atomic_load(p, __ATOMIC_RELAXED, __HIP_MEMORY_SCOPE_AGENT);
}
__device__ __forceinline__ void st_coh(float* p, float v) {
    __hip_atomic_store(p, v, __ATOMIC_RELAXED, __HIP_MEMORY_SCOPE_AGENT);
}

// 8-WG per-batch barrier (R6/R9-proven).
__device__ __forceinline__ void batch_barrier(unsigned* ctr, unsigned target) {
    __syncthreads();
    if (threadIdx.x == 0) {
        asm volatile("s_waitcnt vmcnt(0)" ::: "memory");
        __hip_atomic_fetch_add(ctr, 1u, __ATOMIC_RELAXED, __HIP_MEMORY_SCOPE_AGENT);
        while (__hip_atomic_load(ctr, __ATOMIC_RELAXED, __HIP_MEMORY_SCOPE_AGENT) < target)
            __builtin_amdgcn_s_sleep(8);
    }
    __syncthreads();
}

// ============================================================================
// Register-resident Sinkhorn. 512 WGs x 512 thr, 2 WG/CU co-resident
// (__launch_bounds__(512,4) caps VGPR at 128). Wave owns 8 rows; lane owns
// cols [lane*4..+3] and [256+lane*4..+3]. K = exp2(-c*K2) lives in k[8][8]
// fp32 registers for the whole kernel: c is read ONCE (presweep), then 20
// iterations run from registers with no transcendentals:
//   row:  s_m = sum_n k*v  -> u_m = a_m/s_m
//   col:  ca_n += u_m*k*v  (e-form; v' = b*v/colSum needs no exp2(-g))
// colPart is DOUBLE-BUFFERED (ping-pong by iteration parity) -> the
// read-then-overwrite race R9 had is structurally gone, 1 barrier/iter.
// ============================================================================
template <bool DBUF>
__global__ __launch_bounds__(512, 4) void sink_reg(
    const float* __restrict__ c, const float* __restrict__ amarg,
    const float* __restrict__ bmarg, float* __restrict__ out,
    float* __restrict__ colPart, unsigned* __restrict__ ctr)
{
    __shared__ float sPartial[SLICES][NN];  // 16 KB per-wave col partials
    __shared__ float sV[NN];                //  2 KB current v

    const int wg    = blockIdx.x;
    const int b     = (wg & 7) * 8 + (wg >> 6);   // XCD-clustered batch
    const int slice = (wg >> 3) & 7;
    const int t     = threadIdx.x;
    const int wave  = t >> 6;
    const int lane  = t & 63;

    const int mrow  = slice * 64 + wave * 8;      // this wave's first row
    const float* cw = c   + (size_t)b * MM * NN + (size_t)mrow * NN + lane * 4;
    float*       ow = out + (size_t)b * MM * NN + (size_t)mrow * NN + lane * 4;
    float*    cpB   = colPart + (size_t)b * SLICES * NN;     // buffer-0 slot
    const size_t BUF = (size_t)BB * SLICES * NN;             // 1 MB stride
    unsigned* bc    = ctr + b;

    const float bT = bmarg[b * NN + t];
    float aw[8];
    #pragma unroll
    for (int r = 0; r < 8; ++r) aw[r] = amarg[b * MM + mrow + r];

    // ---- presweep: K into registers; colPart0[n] = sum_m K (u=v=1)
    float k[8][8];
    float ca[8];
    #pragma unroll
    for (int j = 0; j < 8; ++j) ca[j] = 0.f;
    #pragma unroll
    for (int r = 0; r < 8; ++r) {
        const float4 c0 = *(const float4*)(cw + (size_t)r * NN);
        const float4 c1 = *(const float4*)(cw + (size_t)r * NN + 256);
        k[r][0] = exp2fast(c0.x * NEG_K2);  k[r][1] = exp2fast(c0.y * NEG_K2);
        k[r][2] = exp2fast(c0.z * NEG_K2);  k[r][3] = exp2fast(c0.w * NEG_K2);
        k[r][4] = exp2fast(c1.x * NEG_K2);  k[r][5] = exp2fast(c1.y * NEG_K2);
        k[r][6] = exp2fast(c1.z * NEG_K2);  k[r][7] = exp2fast(c1.w * NEG_K2);
        #pragma unroll
        for (int j = 0; j < 8; ++j) ca[j] += k[r][j];
    }
    *(float4*)&sPartial[wave][lane * 4]       = make_float4(ca[0], ca[1], ca[2], ca[3]);
    *(float4*)&sPartial[wave][lane * 4 + 256] = make_float4(ca[4], ca[5], ca[6], ca[7]);
    __syncthreads();
    {
        float p8 = 0.f;
        #pragma unroll
        for (int w = 0; w < SLICES; ++w) p8 += sPartial[w][t];
        st_coh(&cpB[slice * NN + t], p8);   // buffer 0
    }
    unsigned target = SLICES;
    batch_barrier(bc, target);

    // ---- 20 register-resident iterations
    float vold = 1.0f;
    for (int it = 1; it <= NUM_SINK; ++it) {
        const float* rbuf = cpB + (DBUF ? (size_t)((it + 1) & 1) * BUF : 0);
        float*       wbuf = cpB + (DBUF ? (size_t)(it & 1) * BUF       : 0);

        float s8 = 0.f;
        #pragma unroll
        for (int w = 0; w < SLICES; ++w) s8 += ld_coh(&rbuf[w * NN + t]);
        const float v = bT * vold * rcpfast(s8);   // v' = b*v/colSum
        vold = v;
        sV[t] = v;
        if (!DBUF) { target += SLICES; batch_barrier(bc, target); }  // reads done before overwrite
        else       __syncthreads();

        const float4 v0 = *(const float4*)&sV[lane * 4];
        const float4 v1 = *(const float4*)&sV[lane * 4 + 256];
        const bool  last = (it == NUM_SINK);

        #pragma unroll
        for (int j = 0; j < 8; ++j) ca[j] = 0.f;

        #pragma unroll
        for (int r = 0; r < 8; ++r) {
            const float e0 = k[r][0] * v0.x, e1 = k[r][1] * v0.y;
            const float e2 = k[r][2] * v0.z, e3 = k[r][3] * v0.w;
            const float e4 = k[r][4] * v1.x, e5 = k[r][5] * v1.y;
            const float e6 = k[r][6] * v1.z, e7 = k[r][7] * v1.w;
            float s = ((e0 + e1) + (e2 + e3)) + ((e4 + e5) + (e6 + e7));
            #pragma unroll
            for (int o = 32; o > 0; o >>= 1) s += __shfl_xor(s, o, 64);
            const float ts = aw[r] * rcpfast(s);   // = u_m

            if (!last) {
                ca[0] = fmaf(ts, e0, ca[0]);  ca[1] = fmaf(ts, e1, ca[1]);
                ca[2] = fmaf(ts, e2, ca[2]);  ca[3] = fmaf(ts, e3, ca[3]);
                ca[4] = fmaf(ts, e4, ca[4]);  ca[5] = fmaf(ts, e5, ca[5]);
                ca[6] = fmaf(ts, e6, ca[6]);  ca[7] = fmaf(ts, e7, ca[7]);
            } else {                               // p = u * K * v
                *(float4*)(ow + (size_t)r * NN)       =
                    make_float4(ts * e0, ts * e1, ts * e2, ts * e3);
                *(float4*)(ow + (size_t)r * NN + 256) =
                    make_float4(ts * e4, ts * e5, ts * e6, ts * e7);
            }
        }

        if (!last) {
            *(float4*)&sPartial[wave][lane * 4]       = make_float4(ca[0], ca[1], ca[2], ca[3]);
            *(float4*)&sPartial[wave][lane * 4 + 256] = make_float4(ca[4], ca[5], ca[6], ca[7]);
            __syncthreads();
            float p8 = 0.f;
            #pragma unroll
            for (int w = 0; w < SLICES; ++w) p8 += sPartial[w][t];
            st_coh(&wbuf[slice * NN + t], p8);
            target += SLICES;
            batch_barrier(bc, target);
        }
    }
}

// ============================================================================
// Fallback (proven round-1 path, 40 dispatches) if ws < 1 MB (never seen).
// ============================================================================
__device__ __forceinline__ float block_max512(float v, float* sRed) {
    const int t = threadIdx.x;
    float wm = v;
    #pragma unroll
    for (int o = 32; o > 0; o >>= 1) wm = fmaxf(wm, __shfl_xor(wm, o, 64));
    if ((t & 63) == 0) sRed[t >> 6] = wm;
    __syncthreads();
    if (t == 0) {
        float m2 = sRed[0];
        #pragma unroll
        for (int i = 1; i < 8; ++i) m2 = fmaxf(m2, sRed[i]);
        sRed[0] = m2;
    }
    __syncthreads();
    const float r = sRed[0];
    __syncthreads();
    return r;
}

__global__ __launch_bounds__(512) void col_kernel(
    const float* __restrict__ c, const float* __restrict__ bmarg,
    const float* __restrict__ F, float* __restrict__ G, int first)
{
    __shared__ float sF[MM];
    __shared__ float sPart[16][128];
    __shared__ float sRed[8];

    const int b  = blockIdx.x >> 2;
    const int n0 = (blockIdx.x & 3) * 128;
    const int t  = threadIdx.x;

    float maxF = 0.0f, v = 0.0f;
    if (!first) {
        v = F[b * MM + t];
        maxF = block_max512(v, sRed);
    }
    sF[t] = v - maxF;
    __syncthreads();

    const int lane_c = t & 31;
    const int mg     = t >> 5;
    const int n4     = n0 + lane_c * 4;
    const float* cp  = c + (size_t)b * MM * NN;
    const int m0     = mg * 32;

    float s0 = 0.f, s1 = 0.f, s2 = 0.f, s3 = 0.f;
    #pragma unroll 4
    for (int r = 0; r < 32; ++r) {
        const int m = m0 + r;
        const float fp = sF[m];
        const float4 cv = *(const float4*)(cp + (size_t)m * NN + n4);
        s0 += exp2fast(fmaf(cv.x, NEG_K2, fp));
        s1 += exp2fast(fmaf(cv.y, NEG_K2, fp));
        s2 += exp2fast(fmaf(cv.z, NEG_K2, fp));
        s3 += exp2fast(fmaf(cv.w, NEG_K2, fp));
    }
    sPart[mg][lane_c * 4 + 0] = s0;
    sPart[mg][lane_c * 4 + 1] = s1;
    sPart[mg][lane_c * 4 + 2] = s2;
    sPart[mg][lane_c * 4 + 3] = s3;
    __syncthreads();

    if (t < 128) {
        float tot = 0.f;
        #pragma unroll
        for (int g = 0; g < 16; ++g) tot += sPart[g][t];
        const int n = n0 + t;
        G[b * NN + n] = log2fast(bmarg[b * NN + n]) - maxF - log2fast(tot);
    }
}

template <bool WRITE_OUT>
__global__ __launch_bounds__(512) void row_kernel(
    const float* __restrict__ c, const float* __restrict__ amarg,
    const float* __restrict__ G, float* __restrict__ F, float* __restrict__ out)
{
    __shared__ float sG2[NN];
    __shared__ float sRed[8];

    const int b  = blockIdx.x >> 3;
    const int m0 = (blockIdx.x & 7) * 64;
    const int t  = threadIdx.x;

    const float v    = G[b * NN + t];
    const float maxG = block_max512(v, sRed);
    sG2[t] = v - maxG;
    __syncthreads();

    const int wave = t >> 6;
    const int lane = t & 63;
    const float* cp = c + (size_t)b * MM * NN;

    const float4 g0 = *(const float4*)&sG2[lane * 4];
    const float4 g1 = *(const float4*)&sG2[lane * 4 + 256];

    #pragma unroll 2
    for (int r = 0; r < 8; ++r) {
        const int m = m0 + wave * 8 + r;
        const float* rowp = cp + (size_t)m * NN;
        const float4 c0 = *(const float4*)(rowp + lane * 4);
        const float4 c1 = *(const float4*)(rowp + lane * 4 + 256);

        float s = exp2fast(fmaf(c0.x, NEG_K2, g0.x)) + exp2fast(fmaf(c0.y, NEG_K2, g0.y))
                + exp2fast(fmaf(c0.z, NEG_K2, g0.z)) + exp2fast(fmaf(c0.w, NEG_K2, g0.w))
                + exp2fast(fmaf(c1.x, NEG_K2, g1.x)) + exp2fast(fmaf(c1.y, NEG_K2, g1.y))
                + exp2fast(fmaf(c1.z, NEG_K2, g1.z)) + exp2fast(fmaf(c1.w, NEG_K2, g1.w));
        #pragma unroll
        for (int o = 32; o > 0; o >>= 1) s += __shfl_xor(s, o, 64);

        const float Fm = log2fast(amarg[b * MM + m]) - maxG - log2fast(s);
        if (lane == 0) F[b * MM + m] = Fm;

        if (WRITE_OUT) {
            const float base = Fm + maxG;
            float4 o0, o1;
            o0.x = exp2fast(fmaf(c0.x, NEG_K2, base + g0.x));
            o0.y = exp2fast(fmaf(c0.y, NEG_K2, base + g0.y));
            o0.z = exp2fast(fmaf(c0.z, NEG_K2, base + g0.z));
            o0.w = exp2fast(fmaf(c0.w, NEG_K2, base + g0.w));
            o1.x = exp2fast(fmaf(c1.x, NEG_K2, base + g1.x));
            o1.y = exp2fast(fmaf(c1.y, NEG_K2, base + g1.y));
            o1.z = exp2fast(fmaf(c1.z, NEG_K2, base + g1.z));
            o1.w = exp2fast(fmaf(c1.w, NEG_K2, base + g1.w));
            float* op = out + (size_t)b * MM * NN + (size_t)m * NN;
            *(float4*)(op + lane * 4)       = o0;
            *(float4*)(op + lane * 4 + 256) = o1;
        }
    }
}

extern "C" void kernel_launch(void* const* d_in, const int* in_sizes, int n_in,
                              void* d_out, int out_size, void* d_ws, size_t ws_size,
                              hipStream_t stream) {
    const float* c  = (const float*)d_in[0];
    const float* am = (const float*)d_in[1];
    const float* bm = (const float*)d_in[2];
    float* out = (float*)d_out;

    const size_t BUF    = (size_t)BB * SLICES * NN * sizeof(float);  // 1 MB
    const size_t need2  = 2 * BUF + BB * sizeof(unsigned);           // dbuf
    const size_t need1  = 1 * BUF + BB * sizeof(unsigned);           // R9-proven size

    float* colPart = (float*)d_ws;

    if (ws_size >= need2) {
        unsigned* ctr = (unsigned*)((char*)d_ws + 2 * BUF);
        hipMemsetAsync(ctr, 0, BB * sizeof(unsigned), stream);
        hipLaunchKernelGGL((sink_reg<true>), dim3(BB * SLICES), dim3(512), 0, stream,
                           c, am, bm, out, colPart, ctr);
    } else if (ws_size >= need1) {
        unsigned* ctr = (unsigned*)((char*)d_ws + 1 * BUF);
        hipMemsetAsync(ctr, 0, BB * sizeof(unsigned), stream);
        hipLaunchKernelGGL((sink_reg<false>), dim3(BB * SLICES), dim3(512), 0, stream,
                           c, am, bm, out, colPart, ctr);
    } else {
        // fallback: 40-dispatch proven path (needs only 256 KB: F + G)
        float* F = (float*)d_ws;
        float* G = F + BB * MM;
        for (int it = 0; it < NUM_SINK; ++it) {
            hipLaunchKernelGGL(col_kernel, dim3(BB * 4), dim3(512), 0, stream,
                               c, bm, F, G, it == 0 ? 1 : 0);
            if (it < NUM_SINK - 1)
                hipLaunchKernelGGL(row_kernel<false>, dim3(BB * 8), dim3(512), 0, stream,
                                   c, am, G, F, out);
            else
                hipLaunchKernelGGL(row_kernel<true>, dim3(BB * 8), dim3(512), 0, stream,
                                   c, am, G, F, out);
        }
    }
}

// Round 11
// 141.704 us; speedup vs baseline: 2.6615x; 2.6615x over previous
//
#include <hip/hip_runtime.h>

#define BB 64
#define MM 512
#define NN 512
#define NUM_SINK 20
#define SLICES 8   // workgroups per batch

// base-2 domain: exp(x) == exp2(x*log2e); K2 = log2(e)/lambda
constexpr float NEG_K2 = -(1.4426950408889634f / 0.002f);   // ~ -721.3475

__device__ __forceinline__ float exp2fast(float x) { return __builtin_amdgcn_exp2f(x); }
__device__ __forceinline__ float log2fast(float x) { return __builtin_amdgcn_logf(x); }
__device__ __forceinline__ float rcpfast(float x)  { return __builtin_amdgcn_rcpf(x); }

typedef unsigned long long u64;
typedef unsigned u32;

// tagged 8-byte atom: (tag<<32) | float_bits. Aligned 8B st/ld are
// single-copy atomic; AGENT scope -> sc-flagged, served at coherence point.
__device__ __forceinline__ void st_tag(u64* p, float v, u32 tag) {
    u64 x = ((u64)tag << 32) | (u64)__float_as_uint(v);
    __hip_atomic_store(p, x, __ATOMIC_RELAXED, __HIP_MEMORY_SCOPE_AGENT);
}
__device__ __forceinline__ u64 ld_tag(const u64* p) {
    return __hip_atomic_load(p, __ATOMIC_RELAXED, __HIP_MEMORY_SCOPE_AGENT);
}

// ============================================================================
// Barrier-free register-resident Sinkhorn (tagged dataflow).
// 512 WGs x 512 thr, 2 WG/CU co-resident ((512,4): cap 128 VGPR, LDS 18KB).
// Wave owns 8 full rows; K=exp2(-c*K2) lives in k[8][8] regs (c read ONCE).
// Per iteration j: poll 8 tagged slice-partials (tag==j) for own column ->
// v = b*v/colSum -> row sums (wave shfl) -> u=a/s -> next partials tagged j+1
// into the OTHER parity buffer. No global barrier exists at all: readiness
// rides with the data. Parity ping-pong is overwrite-safe by dataflow
// (writing j+2 requires having read all of j+1, which requires all WGs done
// reading j). Tags start at 1; both parity buffers are zeroed by a memset
// node each launch (stale tags from a previous replay would alias).
// ============================================================================
__global__ __launch_bounds__(512, 4) void sink_flow(
    const float* __restrict__ c, const float* __restrict__ amarg,
    const float* __restrict__ bmarg, float* __restrict__ out,
    u64* __restrict__ colTag)          // [2][BB][SLICES][NN]
{
    __shared__ float sPartial[SLICES][NN];  // 16 KB per-wave col partials
    __shared__ float sV[NN];                //  2 KB current v

    const int wg    = blockIdx.x;
    const int b     = (wg & 7) * 8 + (wg >> 6);   // XCD-clustered batch
    const int slice = (wg >> 3) & 7;
    const int t     = threadIdx.x;
    const int wave  = t >> 6;
    const int lane  = t & 63;

    const int mrow  = slice * 64 + wave * 8;      // this wave's first row
    const float* cw = c   + (size_t)b * MM * NN + (size_t)mrow * NN + lane * 4;
    float*       ow = out + (size_t)b * MM * NN + (size_t)mrow * NN + lane * 4;
    const size_t PBUF = (size_t)BB * SLICES * NN;        // entries per parity
    u64* tb         = colTag + (size_t)b * SLICES * NN;  // batch slot, parity 0

    const float bT = bmarg[b * NN + t];
    float aw[8];
    #pragma unroll
    for (int r = 0; r < 8; ++r) aw[r] = amarg[b * MM + mrow + r];

    // ---- presweep: K into registers; partials(u=v=1) tagged 1 -> parity 0
    float k[8][8];
    float ca[8];
    #pragma unroll
    for (int j = 0; j < 8; ++j) ca[j] = 0.f;
    #pragma unroll
    for (int r = 0; r < 8; ++r) {
        const float4 c0 = *(const float4*)(cw + (size_t)r * NN);
        const float4 c1 = *(const float4*)(cw + (size_t)r * NN + 256);
        k[r][0] = exp2fast(c0.x * NEG_K2);  k[r][1] = exp2fast(c0.y * NEG_K2);
        k[r][2] = exp2fast(c0.z * NEG_K2);  k[r][3] = exp2fast(c0.w * NEG_K2);
        k[r][4] = exp2fast(c1.x * NEG_K2);  k[r][5] = exp2fast(c1.y * NEG_K2);
        k[r][6] = exp2fast(c1.z * NEG_K2);  k[r][7] = exp2fast(c1.w * NEG_K2);
        #pragma unroll
        for (int j = 0; j < 8; ++j) ca[j] += k[r][j];
    }
    *(float4*)&sPartial[wave][lane * 4]       = make_float4(ca[0], ca[1], ca[2], ca[3]);
    *(float4*)&sPartial[wave][lane * 4 + 256] = make_float4(ca[4], ca[5], ca[6], ca[7]);
    __syncthreads();
    {
        float p8 = 0.f;
        #pragma unroll
        for (int w = 0; w < SLICES; ++w) p8 += sPartial[w][t];
        st_tag(&tb[slice * NN + t], p8, 1u);
    }

    // ---- 20 dataflow iterations (no barriers)
    float vold = 1.0f;
    for (int j = 1; j <= NUM_SINK; ++j) {
        const u64* rb = colTag + (size_t)((j - 1) & 1) * PBUF + (size_t)b * SLICES * NN;
        u64*       wb = colTag + (size_t)(j & 1) * PBUF       + (size_t)b * SLICES * NN;
        const u32  etag = (u32)j;

        // poll own column's 8 slice-partials until tagged with this iteration
        float s8 = 0.f;
        u32 mask = 0;
        while (mask != 0xFFu) {
            #pragma unroll
            for (int w = 0; w < SLICES; ++w) {
                if (!(mask & (1u << w))) {
                    const u64 x = ld_tag(&rb[w * NN + t]);
                    if ((u32)(x >> 32) == etag) {
                        s8 += __uint_as_float((u32)x);
                        mask |= 1u << w;
                    }
                }
            }
            if (mask != 0xFFu) __builtin_amdgcn_s_sleep(1);
        }

        const float v = bT * vold * rcpfast(s8);   // v' = b*v/colSum
        vold = v;
        sV[t] = v;
        __syncthreads();                            // also orders sPartial reuse

        const float4 v0 = *(const float4*)&sV[lane * 4];
        const float4 v1 = *(const float4*)&sV[lane * 4 + 256];
        const bool  last = (j == NUM_SINK);

        #pragma unroll
        for (int i = 0; i < 8; ++i) ca[i] = 0.f;

        #pragma unroll
        for (int r = 0; r < 8; ++r) {
            const float e0 = k[r][0] * v0.x, e1 = k[r][1] * v0.y;
            const float e2 = k[r][2] * v0.z, e3 = k[r][3] * v0.w;
            const float e4 = k[r][4] * v1.x, e5 = k[r][5] * v1.y;
            const float e6 = k[r][6] * v1.z, e7 = k[r][7] * v1.w;
            float s = ((e0 + e1) + (e2 + e3)) + ((e4 + e5) + (e6 + e7));
            #pragma unroll
            for (int o = 32; o > 0; o >>= 1) s += __shfl_xor(s, o, 64);
            const float ts = aw[r] * rcpfast(s);   // = u_m

            if (!last) {
                ca[0] = fmaf(ts, e0, ca[0]);  ca[1] = fmaf(ts, e1, ca[1]);
                ca[2] = fmaf(ts, e2, ca[2]);  ca[3] = fmaf(ts, e3, ca[3]);
                ca[4] = fmaf(ts, e4, ca[4]);  ca[5] = fmaf(ts, e5, ca[5]);
                ca[6] = fmaf(ts, e6, ca[6]);  ca[7] = fmaf(ts, e7, ca[7]);
            } else {                               // p = u * K * v
                *(float4*)(ow + (size_t)r * NN)       =
                    make_float4(ts * e0, ts * e1, ts * e2, ts * e3);
                *(float4*)(ow + (size_t)r * NN + 256) =
                    make_float4(ts * e4, ts * e5, ts * e6, ts * e7);
            }
        }

        if (!last) {
            *(float4*)&sPartial[wave][lane * 4]       = make_float4(ca[0], ca[1], ca[2], ca[3]);
            *(float4*)&sPartial[wave][lane * 4 + 256] = make_float4(ca[4], ca[5], ca[6], ca[7]);
            __syncthreads();
            float p8 = 0.f;
            #pragma unroll
            for (int w = 0; w < SLICES; ++w) p8 += sPartial[w][t];
            st_tag(&wb[slice * NN + t], p8, (u32)(j + 1));
        }
    }
}

// ============================================================================
// Fallback (proven round-1 path, 40 dispatches) if ws < 4 MB (never seen).
// ============================================================================
__device__ __forceinline__ float block_max512(float v, float* sRed) {
    const int t = threadIdx.x;
    float wm = v;
    #pragma unroll
    for (int o = 32; o > 0; o >>= 1) wm = fmaxf(wm, __shfl_xor(wm, o, 64));
    if ((t & 63) == 0) sRed[t >> 6] = wm;
    __syncthreads();
    if (t == 0) {
        float m2 = sRed[0];
        #pragma unroll
        for (int i = 1; i < 8; ++i) m2 = fmaxf(m2, sRed[i]);
        sRed[0] = m2;
    }
    __syncthreads();
    const float r = sRed[0];
    __syncthreads();
    return r;
}

__global__ __launch_bounds__(512) void col_kernel(
    const float* __restrict__ c, const float* __restrict__ bmarg,
    const float* __restrict__ F, float* __restrict__ G, int first)
{
    __shared__ float sF[MM];
    __shared__ float sPart[16][128];
    __shared__ float sRed[8];

    const int b  = blockIdx.x >> 2;
    const int n0 = (blockIdx.x & 3) * 128;
    const int t  = threadIdx.x;

    float maxF = 0.0f, v = 0.0f;
    if (!first) {
        v = F[b * MM + t];
        maxF = block_max512(v, sRed);
    }
    sF[t] = v - maxF;
    __syncthreads();

    const int lane_c = t & 31;
    const int mg     = t >> 5;
    const int n4     = n0 + lane_c * 4;
    const float* cp  = c + (size_t)b * MM * NN;
    const int m0     = mg * 32;

    float s0 = 0.f, s1 = 0.f, s2 = 0.f, s3 = 0.f;
    #pragma unroll 4
    for (int r = 0; r < 32; ++r) {
        const int m = m0 + r;
        const float fp = sF[m];
        const float4 cv = *(const float4*)(cp + (size_t)m * NN + n4);
        s0 += exp2fast(fmaf(cv.x, NEG_K2, fp));
        s1 += exp2fast(fmaf(cv.y, NEG_K2, fp));
        s2 += exp2fast(fmaf(cv.z, NEG_K2, fp));
        s3 += exp2fast(fmaf(cv.w, NEG_K2, fp));
    }
    sPart[mg][lane_c * 4 + 0] = s0;
    sPart[mg][lane_c * 4 + 1] = s1;
    sPart[mg][lane_c * 4 + 2] = s2;
    sPart[mg][lane_c * 4 + 3] = s3;
    __syncthreads();

    if (t < 128) {
        float tot = 0.f;
        #pragma unroll
        for (int g = 0; g < 16; ++g) tot += sPart[g][t];
        const int n = n0 + t;
        G[b * NN + n] = log2fast(bmarg[b * NN + n]) - maxF - log2fast(tot);
    }
}

template <bool WRITE_OUT>
__global__ __launch_bounds__(512) void row_kernel(
    const float* __restrict__ c, const float* __restrict__ amarg,
    const float* __restrict__ G, float* __restrict__ F, float* __restrict__ out)
{
    __shared__ float sG2[NN];
    __shared__ float sRed[8];

    const int b  = blockIdx.x >> 3;
    const int m0 = (blockIdx.x & 7) * 64;
    const int t  = threadIdx.x;

    const float v    = G[b * NN + t];
    const float maxG = block_max512(v, sRed);
    sG2[t] = v - maxG;
    __syncthreads();

    const int wave = t >> 6;
    const int lane = t & 63;
    const float* cp = c + (size_t)b * MM * NN;

    const float4 g0 = *(const float4*)&sG2[lane * 4];
    const float4 g1 = *(const float4*)&sG2[lane * 4 + 256];

    #pragma unroll 2
    for (int r = 0; r < 8; ++r) {
        const int m = m0 + wave * 8 + r;
        const float* rowp = cp + (size_t)m * NN;
        const float4 c0 = *(const float4*)(rowp + lane * 4);
        const float4 c1 = *(const float4*)(rowp + lane * 4 + 256);

        float s = exp2fast(fmaf(c0.x, NEG_K2, g0.x)) + exp2fast(fmaf(c0.y, NEG_K2, g0.y))
                + exp2fast(fmaf(c0.z, NEG_K2, g0.z)) + exp2fast(fmaf(c0.w, NEG_K2, g0.w))
                + exp2fast(fmaf(c1.x, NEG_K2, g1.x)) + exp2fast(fmaf(c1.y, NEG_K2, g1.y))
                + exp2fast(fmaf(c1.z, NEG_K2, g1.z)) + exp2fast(fmaf(c1.w, NEG_K2, g1.w));
        #pragma unroll
        for (int o = 32; o > 0; o >>= 1) s += __shfl_xor(s, o, 64);

        const float Fm = log2fast(amarg[b * MM + m]) - maxG - log2fast(s);
        if (lane == 0) F[b * MM + m] = Fm;

        if (WRITE_OUT) {
            const float base = Fm + maxG;
            float4 o0, o1;
            o0.x = exp2fast(fmaf(c0.x, NEG_K2, base + g0.x));
            o0.y = exp2fast(fmaf(c0.y, NEG_K2, base + g0.y));
            o0.z = exp2fast(fmaf(c0.z, NEG_K2, base + g0.z));
            o0.w = exp2fast(fmaf(c0.w, NEG_K2, base + g0.w));
            o1.x = exp2fast(fmaf(c1.x, NEG_K2, base + g1.x));
            o1.y = exp2fast(fmaf(c1.y, NEG_K2, base + g1.y));
            o1.z = exp2fast(fmaf(c1.z, NEG_K2, base + g1.z));
            o1.w = exp2fast(fmaf(c1.w, NEG_K2, base + g1.w));
            float* op = out + (size_t)b * MM * NN + (size_t)m * NN;
            *(float4*)(op + lane * 4)       = o0;
            *(float4*)(op + lane * 4 + 256) = o1;
        }
    }
}

extern "C" void kernel_launch(void* const* d_in, const int* in_sizes, int n_in,
                              void* d_out, int out_size, void* d_ws, size_t ws_size,
                              hipStream_t stream) {
    const float* c  = (const float*)d_in[0];
    const float* am = (const float*)d_in[1];
    const float* bm = (const float*)d_in[2];
    float* out = (float*)d_out;

    const size_t TAGBYTES = 2ull * BB * SLICES * NN * sizeof(u64);   // 4 MB

    if (ws_size >= TAGBYTES) {
        u64* colTag = (u64*)d_ws;
        // wipe both parity buffers: stale tags from a previous replay alias
        // current-iteration tags (e.g. leftover tag 19 == iter-19's expected)
        hipMemsetAsync(colTag, 0, TAGBYTES, stream);
        hipLaunchKernelGGL(sink_flow, dim3(BB * SLICES), dim3(512), 0, stream,
                           c, am, bm, out, colTag);
    } else {
        // fallback: 40-dispatch proven path (needs only 256 KB: F + G)
        float* F = (float*)d_ws;
        float* G = F + BB * MM;
        for (int it = 0; it < NUM_SINK; ++it) {
            hipLaunchKernelGGL(col_kernel, dim3(BB * 4), dim3(512), 0, stream,
                               c, bm, F, G, it == 0 ? 1 : 0);
            if (it < NUM_SINK - 1)
                hipLaunchKernelGGL(row_kernel<false>, dim3(BB * 8), dim3(512), 0, stream,
                                   c, am, G, F, out);
            else
                hipLaunchKernelGGL(row_kernel<true>, dim3(BB * 8), dim3(512), 0, stream,
                                   c, am, G, F, out);
        }
    }
}

// Round 12
// 118.426 us; speedup vs baseline: 3.1846x; 1.1966x over previous
//
#include <hip/hip_runtime.h>

#define BB 64
#define MM 512
#define NN 512
#define NUM_SINK 20
#define SLICES 4    // workgroups per batch (1024 threads each)

// base-2 domain: exp(x) == exp2(x*log2e); K2 = log2(e)/lambda
constexpr float NEG_K2 = -(1.4426950408889634f / 0.002f);   // ~ -721.3475

__device__ __forceinline__ float exp2fast(float x) { return __builtin_amdgcn_exp2f(x); }
__device__ __forceinline__ float log2fast(float x) { return __builtin_amdgcn_logf(x); }
__device__ __forceinline__ float rcpfast(float x)  { return __builtin_amdgcn_rcpf(x); }

typedef unsigned long long u64;
typedef unsigned u32;

// tagged 8-byte atom: (tag<<32) | float_bits. Aligned 8B st/ld are
// single-copy atomic; AGENT scope -> sc-flagged, served at coherence point.
__device__ __forceinline__ void st_tag(u64* p, float v, u32 tag) {
    u64 x = ((u64)tag << 32) | (u64)__float_as_uint(v);
    __hip_atomic_store(p, x, __ATOMIC_RELAXED, __HIP_MEMORY_SCOPE_AGENT);
}
__device__ __forceinline__ u64 ld_tag(const u64* p) {
    return __hip_atomic_load(p, __ATOMIC_RELAXED, __HIP_MEMORY_SCOPE_AGENT);
}

// ============================================================================
// Barrier-free register-resident Sinkhorn, congestion-reduced config:
// 256 WGs x 1024 thr (1 WG/CU, 16 waves). 4 WGs per batch (slice owns 128
// rows). K=exp2(-c*K2) in k[8][8] regs per wave-lane; c read ONCE.
// Tagged-dataflow sync (R11-proven): per iteration j, threads t<512 poll the
// batch's 4 slice-partials for column t (tag==j), compute v=b*v/colSum,
// broadcast via LDS; all 16 waves then do register row-sums (u=a/s) and
// accumulate next col partials, LDS-reduced and written tagged j+1 to the
// other parity buffer. vs R11: producers 8->4, readers 8->4, poll issue
// halved (t<512 only) -> ~4x less coherence-point traffic per iteration.
// Tags start at 1; both parity buffers zeroed by a memset node per launch.
// ============================================================================
__global__ __launch_bounds__(1024, 4) void sink_flow4(
    const float* __restrict__ c, const float* __restrict__ amarg,
    const float* __restrict__ bmarg, float* __restrict__ out,
    u64* __restrict__ colTag)          // [2][BB][SLICES][NN]
{
    __shared__ float sPartial[16][NN];      // 32 KB: per-wave col partials
    __shared__ float sV[NN];                //  2 KB: current v

    const int wg    = blockIdx.x;
    const int b     = (wg & 7) * 8 + (wg >> 5);   // XCD-clustered batch
    const int slice = (wg >> 3) & 3;
    const int t     = threadIdx.x;
    const int wave  = t >> 6;                     // 0..15
    const int lane  = t & 63;

    const int mrow  = slice * 128 + wave * 8;     // this wave's first row
    const float* cw = c   + (size_t)b * MM * NN + (size_t)mrow * NN + lane * 4;
    float*       ow = out + (size_t)b * MM * NN + (size_t)mrow * NN + lane * 4;
    const size_t PBUF = (size_t)BB * SLICES * NN;        // entries per parity
    u64* tb         = colTag + (size_t)b * SLICES * NN;  // batch slot, parity 0

    const float bT = (t < NN) ? bmarg[b * NN + t] : 0.f;
    float aw[8];
    #pragma unroll
    for (int r = 0; r < 8; ++r) aw[r] = amarg[b * MM + mrow + r];

    // ---- presweep: K into registers; partials(u=v=1) tagged 1 -> parity 0
    float k[8][8];
    float ca[8];
    #pragma unroll
    for (int j = 0; j < 8; ++j) ca[j] = 0.f;
    #pragma unroll
    for (int r = 0; r < 8; ++r) {
        const float4 c0 = *(const float4*)(cw + (size_t)r * NN);
        const float4 c1 = *(const float4*)(cw + (size_t)r * NN + 256);
        k[r][0] = exp2fast(c0.x * NEG_K2);  k[r][1] = exp2fast(c0.y * NEG_K2);
        k[r][2] = exp2fast(c0.z * NEG_K2);  k[r][3] = exp2fast(c0.w * NEG_K2);
        k[r][4] = exp2fast(c1.x * NEG_K2);  k[r][5] = exp2fast(c1.y * NEG_K2);
        k[r][6] = exp2fast(c1.z * NEG_K2);  k[r][7] = exp2fast(c1.w * NEG_K2);
        #pragma unroll
        for (int j = 0; j < 8; ++j) ca[j] += k[r][j];
    }
    *(float4*)&sPartial[wave][lane * 4]       = make_float4(ca[0], ca[1], ca[2], ca[3]);
    *(float4*)&sPartial[wave][lane * 4 + 256] = make_float4(ca[4], ca[5], ca[6], ca[7]);
    __syncthreads();
    if (t < NN) {
        float p16 = 0.f;
        #pragma unroll
        for (int w = 0; w < 16; ++w) p16 += sPartial[w][t];
        st_tag(&tb[slice * NN + t], p16, 1u);
    }

    // ---- 20 dataflow iterations (no barriers)
    float vold = 1.0f;
    for (int j = 1; j <= NUM_SINK; ++j) {
        const u64* rb = colTag + (size_t)((j - 1) & 1) * PBUF + (size_t)b * SLICES * NN;
        u64*       wb = colTag + (size_t)(j & 1) * PBUF       + (size_t)b * SLICES * NN;
        const u32  etag = (u32)j;

        // threads t<512: poll own column's 4 slice-partials for this iteration
        if (t < NN) {
            float s4 = 0.f;
            u32 mask = 0;
            while (mask != 0xFu) {
                #pragma unroll
                for (int w = 0; w < SLICES; ++w) {
                    if (!(mask & (1u << w))) {
                        const u64 x = ld_tag(&rb[w * NN + t]);
                        if ((u32)(x >> 32) == etag) {
                            s4 += __uint_as_float((u32)x);
                            mask |= 1u << w;
                        }
                    }
                }
                if (mask != 0xFu) __builtin_amdgcn_s_sleep(1);
            }
            const float v = bT * vold * rcpfast(s4);   // v' = b*v/colSum
            vold = v;
            sV[t] = v;
        }
        __syncthreads();                // broadcast v; also orders sPartial reuse

        const float4 v0 = *(const float4*)&sV[lane * 4];
        const float4 v1 = *(const float4*)&sV[lane * 4 + 256];
        const bool  last = (j == NUM_SINK);

        #pragma unroll
        for (int i = 0; i < 8; ++i) ca[i] = 0.f;

        #pragma unroll
        for (int r = 0; r < 8; ++r) {
            const float e0 = k[r][0] * v0.x, e1 = k[r][1] * v0.y;
            const float e2 = k[r][2] * v0.z, e3 = k[r][3] * v0.w;
            const float e4 = k[r][4] * v1.x, e5 = k[r][5] * v1.y;
            const float e6 = k[r][6] * v1.z, e7 = k[r][7] * v1.w;
            float s = ((e0 + e1) + (e2 + e3)) + ((e4 + e5) + (e6 + e7));
            #pragma unroll
            for (int o = 32; o > 0; o >>= 1) s += __shfl_xor(s, o, 64);
            const float ts = aw[r] * rcpfast(s);   // = u_m

            if (!last) {
                ca[0] = fmaf(ts, e0, ca[0]);  ca[1] = fmaf(ts, e1, ca[1]);
                ca[2] = fmaf(ts, e2, ca[2]);  ca[3] = fmaf(ts, e3, ca[3]);
                ca[4] = fmaf(ts, e4, ca[4]);  ca[5] = fmaf(ts, e5, ca[5]);
                ca[6] = fmaf(ts, e6, ca[6]);  ca[7] = fmaf(ts, e7, ca[7]);
            } else {                               // p = u * K * v
                *(float4*)(ow + (size_t)r * NN)       =
                    make_float4(ts * e0, ts * e1, ts * e2, ts * e3);
                *(float4*)(ow + (size_t)r * NN + 256) =
                    make_float4(ts * e4, ts * e5, ts * e6, ts * e7);
            }
        }

        if (!last) {
            *(float4*)&sPartial[wave][lane * 4]       = make_float4(ca[0], ca[1], ca[2], ca[3]);
            *(float4*)&sPartial[wave][lane * 4 + 256] = make_float4(ca[4], ca[5], ca[6], ca[7]);
            __syncthreads();
            if (t < NN) {
                float p16 = 0.f;
                #pragma unroll
                for (int w = 0; w < 16; ++w) p16 += sPartial[w][t];
                st_tag(&wb[slice * NN + t], p16, (u32)(j + 1));
            }
        }
    }
}

// ============================================================================
// Fallback (proven round-1 path, 40 dispatches) if ws < 2 MB (never seen).
// ============================================================================
__device__ __forceinline__ float block_max512(float v, float* sRed) {
    const int t = threadIdx.x;
    float wm = v;
    #pragma unroll
    for (int o = 32; o > 0; o >>= 1) wm = fmaxf(wm, __shfl_xor(wm, o, 64));
    if ((t & 63) == 0) sRed[t >> 6] = wm;
    __syncthreads();
    if (t == 0) {
        float m2 = sRed[0];
        #pragma unroll
        for (int i = 1; i < 8; ++i) m2 = fmaxf(m2, sRed[i]);
        sRed[0] = m2;
    }
    __syncthreads();
    const float r = sRed[0];
    __syncthreads();
    return r;
}

__global__ __launch_bounds__(512) void col_kernel(
    const float* __restrict__ c, const float* __restrict__ bmarg,
    const float* __restrict__ F, float* __restrict__ G, int first)
{
    __shared__ float sF[MM];
    __shared__ float sPart[16][128];
    __shared__ float sRed[8];

    const int b  = blockIdx.x >> 2;
    const int n0 = (blockIdx.x & 3) * 128;
    const int t  = threadIdx.x;

    float maxF = 0.0f, v = 0.0f;
    if (!first) {
        v = F[b * MM + t];
        maxF = block_max512(v, sRed);
    }
    sF[t] = v - maxF;
    __syncthreads();

    const int lane_c = t & 31;
    const int mg     = t >> 5;
    const int n4     = n0 + lane_c * 4;
    const float* cp  = c + (size_t)b * MM * NN;
    const int m0     = mg * 32;

    float s0 = 0.f, s1 = 0.f, s2 = 0.f, s3 = 0.f;
    #pragma unroll 4
    for (int r = 0; r < 32; ++r) {
        const int m = m0 + r;
        const float fp = sF[m];
        const float4 cv = *(const float4*)(cp + (size_t)m * NN + n4);
        s0 += exp2fast(fmaf(cv.x, NEG_K2, fp));
        s1 += exp2fast(fmaf(cv.y, NEG_K2, fp));
        s2 += exp2fast(fmaf(cv.z, NEG_K2, fp));
        s3 += exp2fast(fmaf(cv.w, NEG_K2, fp));
    }
    sPart[mg][lane_c * 4 + 0] = s0;
    sPart[mg][lane_c * 4 + 1] = s1;
    sPart[mg][lane_c * 4 + 2] = s2;
    sPart[mg][lane_c * 4 + 3] = s3;
    __syncthreads();

    if (t < 128) {
        float tot = 0.f;
        #pragma unroll
        for (int g = 0; g < 16; ++g) tot += sPart[g][t];
        const int n = n0 + t;
        G[b * NN + n] = log2fast(bmarg[b * NN + n]) - maxF - log2fast(tot);
    }
}

template <bool WRITE_OUT>
__global__ __launch_bounds__(512) void row_kernel(
    const float* __restrict__ c, const float* __restrict__ amarg,
    const float* __restrict__ G, float* __restrict__ F, float* __restrict__ out)
{
    __shared__ float sG2[NN];
    __shared__ float sRed[8];

    const int b  = blockIdx.x >> 3;
    const int m0 = (blockIdx.x & 7) * 64;
    const int t  = threadIdx.x;

    const float v    = G[b * NN + t];
    const float maxG = block_max512(v, sRed);
    sG2[t] = v - maxG;
    __syncthreads();

    const int wave = t >> 6;
    const int lane = t & 63;
    const float* cp = c + (size_t)b * MM * NN;

    const float4 g0 = *(const float4*)&sG2[lane * 4];
    const float4 g1 = *(const float4*)&sG2[lane * 4 + 256];

    #pragma unroll 2
    for (int r = 0; r < 8; ++r) {
        const int m = m0 + wave * 8 + r;
        const float* rowp = cp + (size_t)m * NN;
        const float4 c0 = *(const float4*)(rowp + lane * 4);
        const float4 c1 = *(const float4*)(rowp + lane * 4 + 256);

        float s = exp2fast(fmaf(c0.x, NEG_K2, g0.x)) + exp2fast(fmaf(c0.y, NEG_K2, g0.y))
                + exp2fast(fmaf(c0.z, NEG_K2, g0.z)) + exp2fast(fmaf(c0.w, NEG_K2, g0.w))
                + exp2fast(fmaf(c1.x, NEG_K2, g1.x)) + exp2fast(fmaf(c1.y, NEG_K2, g1.y))
                + exp2fast(fmaf(c1.z, NEG_K2, g1.z)) + exp2fast(fmaf(c1.w, NEG_K2, g1.w));
        #pragma unroll
        for (int o = 32; o > 0; o >>= 1) s += __shfl_xor(s, o, 64);

        const float Fm = log2fast(amarg[b * MM + m]) - maxG - log2fast(s);
        if (lane == 0) F[b * MM + m] = Fm;

        if (WRITE_OUT) {
            const float base = Fm + maxG;
            float4 o0, o1;
            o0.x = exp2fast(fmaf(c0.x, NEG_K2, base + g0.x));
            o0.y = exp2fast(fmaf(c0.y, NEG_K2, base + g0.y));
            o0.z = exp2fast(fmaf(c0.z, NEG_K2, base + g0.z));
            o0.w = exp2fast(fmaf(c0.w, NEG_K2, base + g0.w));
            o1.x = exp2fast(fmaf(c1.x, NEG_K2, base + g1.x));
            o1.y = exp2fast(fmaf(c1.y, NEG_K2, base + g1.y));
            o1.z = exp2fast(fmaf(c1.z, NEG_K2, base + g1.z));
            o1.w = exp2fast(fmaf(c1.w, NEG_K2, base + g1.w));
            float* op = out + (size_t)b * MM * NN + (size_t)m * NN;
            *(float4*)(op + lane * 4)       = o0;
            *(float4*)(op + lane * 4 + 256) = o1;
        }
    }
}

extern "C" void kernel_launch(void* const* d_in, const int* in_sizes, int n_in,
                              void* d_out, int out_size, void* d_ws, size_t ws_size,
                              hipStream_t stream) {
    const float* c  = (const float*)d_in[0];
    const float* am = (const float*)d_in[1];
    const float* bm = (const float*)d_in[2];
    float* out = (float*)d_out;

    const size_t TAGBYTES = 2ull * BB * SLICES * NN * sizeof(u64);   // 2 MB

    if (ws_size >= TAGBYTES) {
        u64* colTag = (u64*)d_ws;
        // wipe both parity buffers: stale tags from a previous replay alias
        // current-iteration tags (e.g. leftover tag 19 == iter-19's expected)
        hipMemsetAsync(colTag, 0, TAGBYTES, stream);
        hipLaunchKernelGGL(sink_flow4, dim3(BB * SLICES), dim3(1024), 0, stream,
                           c, am, bm, out, colTag);
    } else {
        // fallback: 40-dispatch proven path (needs only 256 KB: F + G)
        float* F = (float*)d_ws;
        float* G = F + BB * MM;
        for (int it = 0; it < NUM_SINK; ++it) {
            hipLaunchKernelGGL(col_kernel, dim3(BB * 4), dim3(512), 0, stream,
                               c, bm, F, G, it == 0 ? 1 : 0);
            if (it < NUM_SINK - 1)
                hipLaunchKernelGGL(row_kernel<false>, dim3(BB * 8), dim3(512), 0, stream,
                                   c, am, G, F, out);
            else
                hipLaunchKernelGGL(row_kernel<true>, dim3(BB * 8), dim3(512), 0, stream,
                                   c, am, G, F, out);
        }
    }
}

// Round 13
// 110.212 us; speedup vs baseline: 3.4220x; 1.0745x over previous
//
#include <hip/hip_runtime.h>

#define BB 64
#define MM 512
#define NN 512
#define NUM_SINK 20
#define SLICES 4    // workgroups per batch (1024 threads each)

// base-2 domain: exp(x) == exp2(x*log2e); K2 = log2(e)/lambda
constexpr float NEG_K2 = -(1.4426950408889634f / 0.002f);   // ~ -721.3475

__device__ __forceinline__ float exp2fast(float x) { return __builtin_amdgcn_exp2f(x); }
__device__ __forceinline__ float log2fast(float x) { return __builtin_amdgcn_logf(x); }
__device__ __forceinline__ float rcpfast(float x)  { return __builtin_amdgcn_rcpf(x); }

typedef unsigned long long u64;
typedef unsigned u32;

// tagged 8-byte atom: (tag<<32) | float_bits. Aligned 8B st/ld are
// single-copy atomic; AGENT scope -> sc-flagged, served at coherence point.
__device__ __forceinline__ void st_tag(u64* p, float v, u32 tag) {
    u64 x = ((u64)tag << 32) | (u64)__float_as_uint(v);
    __hip_atomic_store(p, x, __ATOMIC_RELAXED, __HIP_MEMORY_SCOPE_AGENT);
}
__device__ __forceinline__ u64 ld_tag(const u64* p) {
    return __hip_atomic_load(p, __ATOMIC_RELAXED, __HIP_MEMORY_SCOPE_AGENT);
}

// LDS-only workgroup barrier: orders ds ops without __syncthreads' vmcnt(0)
// drain (which would stall on the fire-and-forget tag store of the previous
// iteration). Memory-clobber asm on both sides + sched_barrier(0) pin LDS
// accesses on their side of the barrier (guide rule 18 discipline).
__device__ __forceinline__ void barrier_lds() {
    asm volatile("s_waitcnt lgkmcnt(0)" ::: "memory");
    __builtin_amdgcn_s_barrier();
    asm volatile("" ::: "memory");
    __builtin_amdgcn_sched_barrier(0);
}

// ============================================================================
// Barrier-free register-resident Sinkhorn (tagged dataflow), R12 structure
// with two serialized-latency fixes:
//  (1) poll loads all 4 slice tags into temps THEN checks (1 RT per round,
//      not 4 serial RTs);
//  (2) in-loop barriers are lgkm-only (no vmcnt drain).
// 256 WGs x 1024 thr (1 WG/CU), 4 WGs per batch, K=exp2(-c*K2) in k[8][8]
// regs, c read ONCE. Tags start at 1; parity buffers zeroed per launch.
// ============================================================================
__global__ __launch_bounds__(1024, 4) void sink_flow5(
    const float* __restrict__ c, const float* __restrict__ amarg,
    const float* __restrict__ bmarg, float* __restrict__ out,
    u64* __restrict__ colTag)          // [2][BB][SLICES][NN]
{
    __shared__ float sPartial[16][NN];      // 32 KB: per-wave col partials
    __shared__ float sV[NN];                //  2 KB: current v

    const int wg    = blockIdx.x;
    const int b     = (wg & 7) * 8 + (wg >> 5);   // XCD-clustered batch
    const int slice = (wg >> 3) & 3;
    const int t     = threadIdx.x;
    const int wave  = t >> 6;                     // 0..15
    const int lane  = t & 63;

    const int mrow  = slice * 128 + wave * 8;     // this wave's first row
    const float* cw = c   + (size_t)b * MM * NN + (size_t)mrow * NN + lane * 4;
    float*       ow = out + (size_t)b * MM * NN + (size_t)mrow * NN + lane * 4;
    const size_t PBUF = (size_t)BB * SLICES * NN;        // entries per parity
    u64* tb         = colTag + (size_t)b * SLICES * NN;  // batch slot, parity 0

    const float bT = (t < NN) ? bmarg[b * NN + t] : 0.f;
    float aw[8];
    #pragma unroll
    for (int r = 0; r < 8; ++r) aw[r] = amarg[b * MM + mrow + r];

    // ---- presweep: K into registers; partials(u=v=1) tagged 1 -> parity 0
    float k[8][8];
    float ca[8];
    #pragma unroll
    for (int j = 0; j < 8; ++j) ca[j] = 0.f;
    #pragma unroll
    for (int r = 0; r < 8; ++r) {
        const float4 c0 = *(const float4*)(cw + (size_t)r * NN);
        const float4 c1 = *(const float4*)(cw + (size_t)r * NN + 256);
        k[r][0] = exp2fast(c0.x * NEG_K2);  k[r][1] = exp2fast(c0.y * NEG_K2);
        k[r][2] = exp2fast(c0.z * NEG_K2);  k[r][3] = exp2fast(c0.w * NEG_K2);
        k[r][4] = exp2fast(c1.x * NEG_K2);  k[r][5] = exp2fast(c1.y * NEG_K2);
        k[r][6] = exp2fast(c1.z * NEG_K2);  k[r][7] = exp2fast(c1.w * NEG_K2);
        #pragma unroll
        for (int j = 0; j < 8; ++j) ca[j] += k[r][j];
    }
    *(float4*)&sPartial[wave][lane * 4]       = make_float4(ca[0], ca[1], ca[2], ca[3]);
    *(float4*)&sPartial[wave][lane * 4 + 256] = make_float4(ca[4], ca[5], ca[6], ca[7]);
    __syncthreads();
    if (t < NN) {
        float p16 = 0.f;
        #pragma unroll
        for (int w = 0; w < 16; ++w) p16 += sPartial[w][t];
        st_tag(&tb[slice * NN + t], p16, 1u);
    }

    // ---- 20 dataflow iterations (no global barriers, lgkm-only WG barriers)
    float vold = 1.0f;
    for (int j = 1; j <= NUM_SINK; ++j) {
        const u64* rb = colTag + (size_t)((j - 1) & 1) * PBUF + (size_t)b * SLICES * NN;
        u64*       wb = colTag + (size_t)(j & 1) * PBUF       + (size_t)b * SLICES * NN;
        const u32  etag = (u32)j;

        // threads t<512: poll all 4 slice tags as a quad (1 RT per round)
        if (t < NN) {
            const u64* p0 = &rb[0 * NN + t];
            const u64* p1 = &rb[1 * NN + t];
            const u64* p2 = &rb[2 * NN + t];
            const u64* p3 = &rb[3 * NN + t];
            u64 x0, x1, x2, x3;
            for (;;) {
                x0 = ld_tag(p0); x1 = ld_tag(p1);
                x2 = ld_tag(p2); x3 = ld_tag(p3);
                const bool ok = ((u32)(x0 >> 32) == etag) & ((u32)(x1 >> 32) == etag)
                              & ((u32)(x2 >> 32) == etag) & ((u32)(x3 >> 32) == etag);
                if (ok) break;
                __builtin_amdgcn_s_sleep(1);
            }
            const float s4 = __uint_as_float((u32)x0) + __uint_as_float((u32)x1)
                           + __uint_as_float((u32)x2) + __uint_as_float((u32)x3);
            const float v = bT * vold * rcpfast(s4);   // v' = b*v/colSum
            vold = v;
            sV[t] = v;
        }
        barrier_lds();                  // broadcast v (LDS-only ordering)

        const float4 v0 = *(const float4*)&sV[lane * 4];
        const float4 v1 = *(const float4*)&sV[lane * 4 + 256];
        const bool  last = (j == NUM_SINK);

        #pragma unroll
        for (int i = 0; i < 8; ++i) ca[i] = 0.f;

        #pragma unroll
        for (int r = 0; r < 8; ++r) {
            const float e0 = k[r][0] * v0.x, e1 = k[r][1] * v0.y;
            const float e2 = k[r][2] * v0.z, e3 = k[r][3] * v0.w;
            const float e4 = k[r][4] * v1.x, e5 = k[r][5] * v1.y;
            const float e6 = k[r][6] * v1.z, e7 = k[r][7] * v1.w;
            float s = ((e0 + e1) + (e2 + e3)) + ((e4 + e5) + (e6 + e7));
            #pragma unroll
            for (int o = 32; o > 0; o >>= 1) s += __shfl_xor(s, o, 64);
            const float ts = aw[r] * rcpfast(s);   // = u_m

            if (!last) {
                ca[0] = fmaf(ts, e0, ca[0]);  ca[1] = fmaf(ts, e1, ca[1]);
                ca[2] = fmaf(ts, e2, ca[2]);  ca[3] = fmaf(ts, e3, ca[3]);
                ca[4] = fmaf(ts, e4, ca[4]);  ca[5] = fmaf(ts, e5, ca[5]);
                ca[6] = fmaf(ts, e6, ca[6]);  ca[7] = fmaf(ts, e7, ca[7]);
            } else {                               // p = u * K * v
                *(float4*)(ow + (size_t)r * NN)       =
                    make_float4(ts * e0, ts * e1, ts * e2, ts * e3);
                *(float4*)(ow + (size_t)r * NN + 256) =
                    make_float4(ts * e4, ts * e5, ts * e6, ts * e7);
            }
        }

        if (!last) {
            *(float4*)&sPartial[wave][lane * 4]       = make_float4(ca[0], ca[1], ca[2], ca[3]);
            *(float4*)&sPartial[wave][lane * 4 + 256] = make_float4(ca[4], ca[5], ca[6], ca[7]);
            barrier_lds();              // sPartial complete (LDS-only ordering)
            if (t < NN) {
                float p16 = 0.f;
                #pragma unroll
                for (int w = 0; w < 16; ++w) p16 += sPartial[w][t];
                st_tag(&wb[slice * NN + t], p16, (u32)(j + 1));
            }
        }
    }
}

// ============================================================================
// Fallback (proven round-1 path, 40 dispatches) if ws < 2 MB (never seen).
// ============================================================================
__device__ __forceinline__ float block_max512(float v, float* sRed) {
    const int t = threadIdx.x;
    float wm = v;
    #pragma unroll
    for (int o = 32; o > 0; o >>= 1) wm = fmaxf(wm, __shfl_xor(wm, o, 64));
    if ((t & 63) == 0) sRed[t >> 6] = wm;
    __syncthreads();
    if (t == 0) {
        float m2 = sRed[0];
        #pragma unroll
        for (int i = 1; i < 8; ++i) m2 = fmaxf(m2, sRed[i]);
        sRed[0] = m2;
    }
    __syncthreads();
    const float r = sRed[0];
    __syncthreads();
    return r;
}

__global__ __launch_bounds__(512) void col_kernel(
    const float* __restrict__ c, const float* __restrict__ bmarg,
    const float* __restrict__ F, float* __restrict__ G, int first)
{
    __shared__ float sF[MM];
    __shared__ float sPart[16][128];
    __shared__ float sRed[8];

    const int b  = blockIdx.x >> 2;
    const int n0 = (blockIdx.x & 3) * 128;
    const int t  = threadIdx.x;

    float maxF = 0.0f, v = 0.0f;
    if (!first) {
        v = F[b * MM + t];
        maxF = block_max512(v, sRed);
    }
    sF[t] = v - maxF;
    __syncthreads();

    const int lane_c = t & 31;
    const int mg     = t >> 5;
    const int n4     = n0 + lane_c * 4;
    const float* cp  = c + (size_t)b * MM * NN;
    const int m0     = mg * 32;

    float s0 = 0.f, s1 = 0.f, s2 = 0.f, s3 = 0.f;
    #pragma unroll 4
    for (int r = 0; r < 32; ++r) {
        const int m = m0 + r;
        const float fp = sF[m];
        const float4 cv = *(const float4*)(cp + (size_t)m * NN + n4);
        s0 += exp2fast(fmaf(cv.x, NEG_K2, fp));
        s1 += exp2fast(fmaf(cv.y, NEG_K2, fp));
        s2 += exp2fast(fmaf(cv.z, NEG_K2, fp));
        s3 += exp2fast(fmaf(cv.w, NEG_K2, fp));
    }
    sPart[mg][lane_c * 4 + 0] = s0;
    sPart[mg][lane_c * 4 + 1] = s1;
    sPart[mg][lane_c * 4 + 2] = s2;
    sPart[mg][lane_c * 4 + 3] = s3;
    __syncthreads();

    if (t < 128) {
        float tot = 0.f;
        #pragma unroll
        for (int g = 0; g < 16; ++g) tot += sPart[g][t];
        const int n = n0 + t;
        G[b * NN + n] = log2fast(bmarg[b * NN + n]) - maxF - log2fast(tot);
    }
}

template <bool WRITE_OUT>
__global__ __launch_bounds__(512) void row_kernel(
    const float* __restrict__ c, const float* __restrict__ amarg,
    const float* __restrict__ G, float* __restrict__ F, float* __restrict__ out)
{
    __shared__ float sG2[NN];
    __shared__ float sRed[8];

    const int b  = blockIdx.x >> 3;
    const int m0 = (blockIdx.x & 7) * 64;
    const int t  = threadIdx.x;

    const float v    = G[b * NN + t];
    const float maxG = block_max512(v, sRed);
    sG2[t] = v - maxG;
    __syncthreads();

    const int wave = t >> 6;
    const int lane = t & 63;
    const float* cp = c + (size_t)b * MM * NN;

    const float4 g0 = *(const float4*)&sG2[lane * 4];
    const float4 g1 = *(const float4*)&sG2[lane * 4 + 256];

    #pragma unroll 2
    for (int r = 0; r < 8; ++r) {
        const int m = m0 + wave * 8 + r;
        const float* rowp = cp + (size_t)m * NN;
        const float4 c0 = *(const float4*)(rowp + lane * 4);
        const float4 c1 = *(const float4*)(rowp + lane * 4 + 256);

        float s = exp2fast(fmaf(c0.x, NEG_K2, g0.x)) + exp2fast(fmaf(c0.y, NEG_K2, g0.y))
                + exp2fast(fmaf(c0.z, NEG_K2, g0.z)) + exp2fast(fmaf(c0.w, NEG_K2, g0.w))
                + exp2fast(fmaf(c1.x, NEG_K2, g1.x)) + exp2fast(fmaf(c1.y, NEG_K2, g1.y))
                + exp2fast(fmaf(c1.z, NEG_K2, g1.z)) + exp2fast(fmaf(c1.w, NEG_K2, g1.w));
        #pragma unroll
        for (int o = 32; o > 0; o >>= 1) s += __shfl_xor(s, o, 64);

        const float Fm = log2fast(amarg[b * MM + m]) - maxG - log2fast(s);
        if (lane == 0) F[b * MM + m] = Fm;

        if (WRITE_OUT) {
            const float base = Fm + maxG;
            float4 o0, o1;
            o0.x = exp2fast(fmaf(c0.x, NEG_K2, base + g0.x));
            o0.y = exp2fast(fmaf(c0.y, NEG_K2, base + g0.y));
            o0.z = exp2fast(fmaf(c0.z, NEG_K2, base + g0.z));
            o0.w = exp2fast(fmaf(c0.w, NEG_K2, base + g0.w));
            o1.x = exp2fast(fmaf(c1.x, NEG_K2, base + g1.x));
            o1.y = exp2fast(fmaf(c1.y, NEG_K2, base + g1.y));
            o1.z = exp2fast(fmaf(c1.z, NEG_K2, base + g1.z));
            o1.w = exp2fast(fmaf(c1.w, NEG_K2, base + g1.w));
            float* op = out + (size_t)b * MM * NN + (size_t)m * NN;
            *(float4*)(op + lane * 4)       = o0;
            *(float4*)(op + lane * 4 + 256) = o1;
        }
    }
}

extern "C" void kernel_launch(void* const* d_in, const int* in_sizes, int n_in,
                              void* d_out, int out_size, void* d_ws, size_t ws_size,
                              hipStream_t stream) {
    const float* c  = (const float*)d_in[0];
    const float* am = (const float*)d_in[1];
    const float* bm = (const float*)d_in[2];
    float* out = (float*)d_out;

    const size_t TAGBYTES = 2ull * BB * SLICES * NN * sizeof(u64);   // 2 MB

    if (ws_size >= TAGBYTES) {
        u64* colTag = (u64*)d_ws;
        // wipe both parity buffers: stale tags from a previous replay alias
        // current-iteration tags (e.g. leftover tag 19 == iter-19's expected)
        hipMemsetAsync(colTag, 0, TAGBYTES, stream);
        hipLaunchKernelGGL(sink_flow5, dim3(BB * SLICES), dim3(1024), 0, stream,
                           c, am, bm, out, colTag);
    } else {
        // fallback: 40-dispatch proven path (needs only 256 KB: F + G)
        float* F = (float*)d_ws;
        float* G = F + BB * MM;
        for (int it = 0; it < NUM_SINK; ++it) {
            hipLaunchKernelGGL(col_kernel, dim3(BB * 4), dim3(512), 0, stream,
                               c, bm, F, G, it == 0 ? 1 : 0);
            if (it < NUM_SINK - 1)
                hipLaunchKernelGGL(row_kernel<false>, dim3(BB * 8), dim3(512), 0, stream,
                                   c, am, G, F, out);
            else
                hipLaunchKernelGGL(row_kernel<true>, dim3(BB * 8), dim3(512), 0, stream,
                                   c, am, G, F, out);
        }
    }
}